// Round 5
// baseline (4616.454 us; speedup 1.0000x reference)
//
#include <hip/hip_runtime.h>

#define TLEN 512
#define FIN 16

__device__ __forceinline__ float sigm(float x) { return 1.0f / (1.0f + __expf(-x)); }
__device__ __forceinline__ float tanh_f(float x) {
  x = fminf(fmaxf(x, -15.0f), 15.0f);
  float e = __expf(2.0f * x);
  return (e - 1.0f) / (e + 1.0f);
}

// R5: batch-split waves, 3 gate columns per lane (no shfl, no role masking),
// K=4 timesteps per barrier interval (133 intervals instead of 516).
//   w0: L0 batch A (lane=unit, 64)   + k3.h2 partials steps 0,1 (both batches)
//   w1: L0 batch B                   + k3.h2 partials steps 2,3 + obuf flush
//   w2: L1 both batches (lane: b=l>>5, u=l&31)
//   w3: L2 + L3-final, both batches
// All h-state LDS reads are wave-uniform (or 2-group) broadcasts; each lane's
// own recurrent h value lives in a register. Weight arrays W1/W2/W3 are shared
// across roles so branch register sets don't sum (R2 spill lesson).
__global__ __launch_bounds__(256, 1)
void rnn_k4(const float* __restrict__ x, const float* __restrict__ emb,
            const float* __restrict__ k0, const float* __restrict__ r0,
            const float* __restrict__ bi0, const float* __restrict__ bh0,
            const float* __restrict__ k1, const float* __restrict__ r1,
            const float* __restrict__ bi1, const float* __restrict__ bh1,
            const float* __restrict__ k2, const float* __restrict__ r2,
            const float* __restrict__ bi2, const float* __restrict__ bh2,
            const float* __restrict__ k3, const float* __restrict__ r3,
            const float* __restrict__ bi3, const float* __restrict__ bh3,
            const float* __restrict__ w1, const float* __restrict__ b1,
            const float* __restrict__ w2, const float* __restrict__ b2,
            const float* __restrict__ vv, const float* __restrict__ bv,
            const float* __restrict__ wd, const float* __restrict__ bd,
            float* __restrict__ out, float* __restrict__ obuf)
{
  __shared__ __align__(16) float s_xin[2][TLEN][20];     // 80 KB [batch][t][19+pad]
  __shared__ __align__(16) float s_h0[2][8][64];         // 4 KB ring (2 intervals)
  __shared__ __align__(16) float s_h1[2][8][32];         // 2 KB
  __shared__ __align__(16) float s_h2[2][8][32];
  __shared__ __align__(16) float s_h3[2][8][32];
  __shared__ __align__(16) float s_pA[2][4][2][3][32];   // k3.h2 partials, 6 KB
  __shared__ __align__(16) float s_fl[2][4][2][32];      // h3 flush ring, 2 KB
  // epilogue
  __shared__ __align__(16) float e_w1[1024];
  __shared__ __align__(16) float e_sc[1024];
  __shared__ float e_hw2[64], e_b1[32], e_v[32], e_ctx[64];

  const int tid  = threadIdx.x;
  const int wid  = tid >> 6;
  const int lane = tid & 63;
  const int bb0  = blockIdx.x * 2;

  float W1[192], W2[96], W3[96];
  float bz=0.f, br=0.f, bxh=0.f, bhh=0.f;      // primary layer biases
  float cz=0.f, cr=0.f, cxh=0.f, chh=0.f;      // w3's L3 biases

  // ---------------- weight loading (registers, role-shared arrays) ---------
  if (wid <= 1) {                 // L0: lane u owns unit u (cols u, 64+u, 128+u)
    const int u = lane;
    #pragma unroll
    for (int g = 0; g < 3; ++g)
      #pragma unroll
      for (int j = 0; j < 64; ++j) W1[g*64+j] = r0[j*192 + g*64 + u];
    #pragma unroll
    for (int g = 0; g < 3; ++g)
      #pragma unroll
      for (int j = 0; j < 19; ++j) W2[g*19+j] = k0[j*192 + g*64 + u];
    const int ku = lane & 31;     // k3 partial weights (unit ku of L3)
    #pragma unroll
    for (int g = 0; g < 3; ++g)
      #pragma unroll
      for (int j = 0; j < 32; ++j) W3[g*32+j] = k3[j*96 + g*32 + ku];
    bz  = bi0[u]      + bh0[u];
    br  = bi0[64+u]   + bh0[64+u];
    bxh = bi0[128+u];
    bhh = bh0[128+u];
  } else if (wid == 2) {          // L1
    const int u = lane & 31;
    #pragma unroll
    for (int g = 0; g < 3; ++g)
      #pragma unroll
      for (int j = 0; j < 64; ++j) W1[g*64+j] = k1[j*96 + g*32 + u];
    #pragma unroll
    for (int g = 0; g < 3; ++g)
      #pragma unroll
      for (int j = 0; j < 32; ++j) W2[g*32+j] = r1[j*96 + g*32 + u];
    bz  = bi1[u]     + bh1[u];
    br  = bi1[32+u]  + bh1[32+u];
    bxh = bi1[64+u];
    bhh = bh1[64+u];
  } else {                        // L2 (+L3 final)
    const int u = lane & 31;
    #pragma unroll
    for (int g = 0; g < 3; ++g)
      #pragma unroll
      for (int j = 0; j < 32; ++j) W1[g*32+j] = k2[j*96 + g*32 + u];
    #pragma unroll
    for (int g = 0; g < 3; ++g)
      #pragma unroll
      for (int j = 0; j < 32; ++j) W1[96 + g*32+j] = r2[j*96 + g*32 + u];
    #pragma unroll
    for (int g = 0; g < 3; ++g)
      #pragma unroll
      for (int j = 0; j < 32; ++j) W2[g*32+j] = r3[j*96 + g*32 + u];
    bz  = bi2[u]     + bh2[u];
    br  = bi2[32+u]  + bh2[32+u];
    bxh = bi2[64+u];
    bhh = bh2[64+u];
    cz  = bi3[u]     + bh3[u];
    cr  = bi3[32+u]  + bh3[32+u];
    cxh = bi3[64+u];
    chh = bh3[64+u];
  }

  // ---------------- zero rings ----------------
  for (int q = tid; q < 1024; q += 256) ((float*)s_h0)[q] = 0.f;
  for (int q = tid; q < 512; q += 256) {
    ((float*)s_h1)[q] = 0.f; ((float*)s_h2)[q] = 0.f; ((float*)s_h3)[q] = 0.f;
  }

  // ---------------- stage full input into LDS ----------------
  for (int r = tid; r < 2*TLEN; r += 256) {
    const int b = r >> 9, t = r & 511;
    const float* xr = &x[((size_t)(bb0 + b) * TLEN + t) * FIN];
    const float4 x0 = *(const float4*)(xr);
    const float4 x1 = *(const float4*)(xr + 4);
    const float4 x2 = *(const float4*)(xr + 8);
    const float4 x3 = *(const float4*)(xr + 12);
    const int id = (int)x0.y;
    const float4 e4 = *(const float4*)&emb[id * 4];
    float4* dst = (float4*)&s_xin[b][t][0];
    dst[0] = make_float4(x0.x, x0.z, x0.w, x1.x);
    dst[1] = make_float4(x1.y, x1.z, x1.w, x2.x);
    dst[2] = make_float4(x2.y, x2.z, x2.w, x3.x);
    dst[3] = make_float4(x3.y, x3.z, x3.w, e4.x);
    dst[4] = make_float4(e4.y, e4.z, e4.w, 0.f);
  }

  float hold0 = 0.f, hold1 = 0.f, hold2 = 0.f, hold3 = 0.f;

  // ---------------- pipelined recurrence: 133 intervals x 4 steps ----------
  for (int I = 0; I < 133; ++I) {
    __syncthreads();

    if (wid <= 1) {
      const int b = wid;
      // ---- k3.h2 partials (t = 4(I-3)+s), w0: s=0,1  w1: s=2,3
      if (I >= 3 && I < 131) {
        const int kb = lane >> 5, ku = lane & 31;
        #pragma unroll
        for (int s2 = 0; s2 < 2; ++s2) {
          const int s = wid*2 + s2;
          const int t = 4*(I-3) + s, sl = t & 7;
          float pz = 0.f, pr = 0.f, ph = 0.f;
          #pragma unroll
          for (int j4 = 0; j4 < 8; ++j4) {
            const float4 h4 = *(const float4*)&s_h2[kb][sl][j4*4];
            pz += W3[j4*4]*h4.x + W3[j4*4+1]*h4.y + W3[j4*4+2]*h4.z + W3[j4*4+3]*h4.w;
            pr += W3[32+j4*4]*h4.x + W3[32+j4*4+1]*h4.y + W3[32+j4*4+2]*h4.z + W3[32+j4*4+3]*h4.w;
            ph += W3[64+j4*4]*h4.x + W3[64+j4*4+1]*h4.y + W3[64+j4*4+2]*h4.z + W3[64+j4*4+3]*h4.w;
          }
          const int pp = I & 1;
          s_pA[pp][s][kb][0][ku] = pz;
          s_pA[pp][s][kb][1][ku] = pr;
          s_pA[pp][s][kb][2][ku] = ph;
        }
      }
      // ---- w1: flush previous interval's h3 chunk to obuf (coalesced)
      if (wid == 1 && I >= 5) {
        const int par = (I-1) & 1, t0 = 4*(I-5);
        const int s = lane >> 4, fb = (lane >> 3) & 1, u0 = (lane & 7) * 4;
        const float4 vq = *(const float4*)&s_fl[par][s][fb][u0];
        *(float4*)&obuf[((size_t)(bb0+fb)*TLEN + t0 + s)*32 + u0] = vq;
      }
      // ---- L0, 4 steps t=4I..4I+3
      if (I < 128) {
        const int u = lane;
        #pragma unroll
        for (int s = 0; s < 4; ++s) {
          const int t = 4*I + s;
          const int ps = (t-1) & 7, ws = t & 7;
          float az = bz, ar = br, ahx = bxh, ph = bhh;
          float xa[20];
          {
            const float* xv = &s_xin[b][t][0];
            *(float4*)&xa[0]  = *(const float4*)(xv);
            *(float4*)&xa[4]  = *(const float4*)(xv+4);
            *(float4*)&xa[8]  = *(const float4*)(xv+8);
            *(float4*)&xa[12] = *(const float4*)(xv+12);
            *(float4*)&xa[16] = *(const float4*)(xv+16);
          }
          #pragma unroll
          for (int j = 0; j < 19; ++j) {
            az += W2[j]*xa[j]; ar += W2[19+j]*xa[j]; ahx += W2[38+j]*xa[j];
          }
          #pragma unroll
          for (int j4 = 0; j4 < 16; ++j4) {
            const float4 h4 = *(const float4*)&s_h0[b][ps][j4*4];
            az  += W1[j4*4]*h4.x + W1[j4*4+1]*h4.y + W1[j4*4+2]*h4.z + W1[j4*4+3]*h4.w;
            ar  += W1[64+j4*4]*h4.x + W1[64+j4*4+1]*h4.y + W1[64+j4*4+2]*h4.z + W1[64+j4*4+3]*h4.w;
            ph  += W1[128+j4*4]*h4.x + W1[128+j4*4+1]*h4.y + W1[128+j4*4+2]*h4.z + W1[128+j4*4+3]*h4.w;
          }
          const float z = sigm(az), r = sigm(ar);
          const float hh = tanh_f(ahx + r*ph);
          hold0 = z*hold0 + (1.f - z)*hh;
          s_h0[b][ws][u] = hold0;
        }
      }
    } else if (wid == 2) {
      // ---- L1, t = 4(I-1)+s, both batches (half-wave each)
      if (I >= 1 && I < 129) {
        const int b = lane >> 5, u = lane & 31;
        #pragma unroll
        for (int s = 0; s < 4; ++s) {
          const int t = 4*(I-1) + s;
          const int ps = (t-1) & 7, ws = t & 7;
          float az = bz, ar = br, ahx = bxh, ph = bhh;
          #pragma unroll
          for (int j4 = 0; j4 < 16; ++j4) {
            const float4 h4 = *(const float4*)&s_h0[b][ws][j4*4];   // h0[t]
            az  += W1[j4*4]*h4.x + W1[j4*4+1]*h4.y + W1[j4*4+2]*h4.z + W1[j4*4+3]*h4.w;
            ar  += W1[64+j4*4]*h4.x + W1[64+j4*4+1]*h4.y + W1[64+j4*4+2]*h4.z + W1[64+j4*4+3]*h4.w;
            ahx += W1[128+j4*4]*h4.x + W1[128+j4*4+1]*h4.y + W1[128+j4*4+2]*h4.z + W1[128+j4*4+3]*h4.w;
          }
          #pragma unroll
          for (int j4 = 0; j4 < 8; ++j4) {
            const float4 h4 = *(const float4*)&s_h1[b][ps][j4*4];   // h1[t-1]
            az += W2[j4*4]*h4.x + W2[j4*4+1]*h4.y + W2[j4*4+2]*h4.z + W2[j4*4+3]*h4.w;
            ar += W2[32+j4*4]*h4.x + W2[32+j4*4+1]*h4.y + W2[32+j4*4+2]*h4.z + W2[32+j4*4+3]*h4.w;
            ph += W2[64+j4*4]*h4.x + W2[64+j4*4+1]*h4.y + W2[64+j4*4+2]*h4.z + W2[64+j4*4+3]*h4.w;
          }
          const float z = sigm(az), r = sigm(ar);
          const float hh = tanh_f(ahx + r*ph);
          hold1 = z*hold1 + (1.f - z)*hh;
          s_h1[b][ws][u] = hold1;
        }
      }
    } else {
      const int b = lane >> 5, u = lane & 31;
      // ---- L2, t = 4(I-2)+s
      if (I >= 2 && I < 130) {
        #pragma unroll
        for (int s = 0; s < 4; ++s) {
          const int t = 4*(I-2) + s;
          const int ps = (t-1) & 7, ws = t & 7;
          float az = bz, ar = br, ahx = bxh, ph = bhh;
          #pragma unroll
          for (int j4 = 0; j4 < 8; ++j4) {
            const float4 h4 = *(const float4*)&s_h1[b][ws][j4*4];   // h1[t]
            az  += W1[j4*4]*h4.x + W1[j4*4+1]*h4.y + W1[j4*4+2]*h4.z + W1[j4*4+3]*h4.w;
            ar  += W1[32+j4*4]*h4.x + W1[32+j4*4+1]*h4.y + W1[32+j4*4+2]*h4.z + W1[32+j4*4+3]*h4.w;
            ahx += W1[64+j4*4]*h4.x + W1[64+j4*4+1]*h4.y + W1[64+j4*4+2]*h4.z + W1[64+j4*4+3]*h4.w;
          }
          #pragma unroll
          for (int j4 = 0; j4 < 8; ++j4) {
            const float4 h4 = *(const float4*)&s_h2[b][ps][j4*4];   // h2[t-1]
            az += W1[96+j4*4]*h4.x + W1[96+j4*4+1]*h4.y + W1[96+j4*4+2]*h4.z + W1[96+j4*4+3]*h4.w;
            ar += W1[128+j4*4]*h4.x + W1[128+j4*4+1]*h4.y + W1[128+j4*4+2]*h4.z + W1[128+j4*4+3]*h4.w;
            ph += W1[160+j4*4]*h4.x + W1[160+j4*4+1]*h4.y + W1[160+j4*4+2]*h4.z + W1[160+j4*4+3]*h4.w;
          }
          const float z = sigm(az), r = sigm(ar);
          const float hh = tanh_f(ahx + r*ph);
          hold2 = z*hold2 + (1.f - z)*hh;
          s_h2[b][ws][u] = hold2;
        }
      }
      // ---- L3 final, t = 4(I-4)+s  (k3 part comes from s_pA)
      if (I >= 4 && I < 132) {
        #pragma unroll
        for (int s = 0; s < 4; ++s) {
          const int t = 4*(I-4) + s;
          const int ps = (t-1) & 7, ws = t & 7;
          float sz = 0.f, sr = 0.f, sh = 0.f;
          #pragma unroll
          for (int j4 = 0; j4 < 8; ++j4) {
            const float4 h4 = *(const float4*)&s_h3[b][ps][j4*4];   // h3[t-1]
            sz += W2[j4*4]*h4.x + W2[j4*4+1]*h4.y + W2[j4*4+2]*h4.z + W2[j4*4+3]*h4.w;
            sr += W2[32+j4*4]*h4.x + W2[32+j4*4+1]*h4.y + W2[32+j4*4+2]*h4.z + W2[32+j4*4+3]*h4.w;
            sh += W2[64+j4*4]*h4.x + W2[64+j4*4+1]*h4.y + W2[64+j4*4+2]*h4.z + W2[64+j4*4+3]*h4.w;
          }
          const int pp = (I-1) & 1;
          const float pz  = s_pA[pp][s][b][0][u];
          const float pr  = s_pA[pp][s][b][1][u];
          const float phh = s_pA[pp][s][b][2][u];
          const float z = sigm(pz + sz + cz);
          const float r = sigm(pr + sr + cr);
          const float hh = tanh_f((phh + cxh) + r*(sh + chh));
          hold3 = z*hold3 + (1.f - z)*hh;
          s_h3[b][ws][u] = hold3;
          s_fl[I & 1][s][b][u] = hold3;
        }
      }
    }
  }
  __syncthreads();

  // ---------------- attention epilogue (hT = s_h3[b][7][:]) ----------------
  for (int kk = tid; kk < 1024; kk += 256) e_w1[kk] = w1[kk];
  if (tid < 32) { e_b1[tid] = b1[tid]; e_v[tid] = vv[tid]; }
  if (tid >= 64 && tid < 128) {
    const int u = tid & 31, bb = (tid - 64) >> 5;
    float s = b2[u];
    #pragma unroll
    for (int j = 0; j < 32; ++j) s += s_h3[bb][7][j] * w2[j*32 + u];
    e_hw2[bb*32 + u] = s;
  }
  __syncthreads();

  #pragma unroll
  for (int c = 0; c < 4; ++c) {   // scores: 1024 tasks (2 batches x 512 t)
    const int idx = c*256 + tid;
    const int bb = idx >> 9, t2 = idx & 511;
    const float* row = obuf + ((size_t)(bb0+bb)*TLEN + t2)*32;
    float rr[32];
    #pragma unroll
    for (int j = 0; j < 32; j += 4) {
      const float4 r4 = *(const float4*)&row[j];
      rr[j]=r4.x; rr[j+1]=r4.y; rr[j+2]=r4.z; rr[j+3]=r4.w;
    }
    float sc = 0.f;
    for (int u = 0; u < 32; ++u) {
      float qv = e_b1[u] + e_hw2[bb*32 + u];
      #pragma unroll
      for (int j = 0; j < 32; ++j) qv += rr[j]*e_w1[j*32+u];
      sc += tanh_f(qv)*e_v[u];
    }
    e_sc[idx] = sc;    // bv dropped: constant shift cancels in softmax
  }
  __syncthreads();

  {  // softmax over T per batch: wave 0 -> b=0, wave 1 -> b=1
    if (wid < 2) {
      const int bb = wid;
      float sv[8]; float m = -1e30f;
      #pragma unroll
      for (int k = 0; k < 8; ++k) { sv[k] = e_sc[bb*512 + lane + 64*k]; m = fmaxf(m, sv[k]); }
      #pragma unroll
      for (int off = 32; off > 0; off >>= 1) m = fmaxf(m, __shfl_xor(m, off));
      float ss = 0.f;
      #pragma unroll
      for (int k = 0; k < 8; ++k) { sv[k] = __expf(sv[k]-m); ss += sv[k]; }
      #pragma unroll
      for (int off = 32; off > 0; off >>= 1) ss += __shfl_xor(ss, off);
      const float inv = 1.f/ss;
      #pragma unroll
      for (int k = 0; k < 8; ++k) e_sc[bb*512 + lane + 64*k] = sv[k]*inv;
    }
  }
  __syncthreads();

  if (tid < 64) {     // ctx = sum_t p_t * out_t (coalesced across u)
    const int u = tid & 31, bb = tid >> 5;
    float acc = 0.f;
    const float* orow = obuf + (size_t)(bb0+bb)*TLEN*32 + u;
    const float* prow = e_sc + bb*512;
    #pragma unroll 4
    for (int t2 = 0; t2 < 512; ++t2) acc += prow[t2]*orow[(size_t)t2*32];
    e_ctx[bb*32 + u] = acc;
  }
  __syncthreads();

  if (tid < 2) {      // final 2-class softmax
    const int bb = tid;
    float l0 = bd[0], l1 = bd[1];
    #pragma unroll
    for (int u = 0; u < 32; ++u) {
      const float cv = e_ctx[bb*32 + u];
      l0 += cv*wd[u*2]; l1 += cv*wd[u*2+1];
    }
    const float mm = fmaxf(l0, l1);
    const float ex0 = __expf(l0-mm), ex1 = __expf(l1-mm);
    const float den = ex0 + ex1;
    out[(bb0+bb)*2 + 0] = ex0/den;
    out[(bb0+bb)*2 + 1] = ex1/den;
  }
}

extern "C" void kernel_launch(void* const* d_in, const int* in_sizes, int n_in,
                              void* d_out, int out_size, void* d_ws, size_t ws_size,
                              hipStream_t stream) {
  const float* x   = (const float*)d_in[0];
  const float* emb = (const float*)d_in[1];
  const float* k0  = (const float*)d_in[2];
  const float* r0  = (const float*)d_in[3];
  const float* bi0 = (const float*)d_in[4];
  const float* bh0 = (const float*)d_in[5];
  const float* k1  = (const float*)d_in[6];
  const float* r1  = (const float*)d_in[7];
  const float* bi1 = (const float*)d_in[8];
  const float* bh1 = (const float*)d_in[9];
  const float* k2  = (const float*)d_in[10];
  const float* r2  = (const float*)d_in[11];
  const float* bi2 = (const float*)d_in[12];
  const float* bh2 = (const float*)d_in[13];
  const float* k3  = (const float*)d_in[14];
  const float* r3  = (const float*)d_in[15];
  const float* bi3 = (const float*)d_in[16];
  const float* bh3 = (const float*)d_in[17];
  const float* w1  = (const float*)d_in[18];
  const float* b1  = (const float*)d_in[19];
  const float* w2  = (const float*)d_in[20];
  const float* b2  = (const float*)d_in[21];
  const float* v   = (const float*)d_in[22];
  const float* bv  = (const float*)d_in[23];
  const float* wd  = (const float*)d_in[24];
  const float* bd  = (const float*)d_in[25];

  float* out  = (float*)d_out;
  float* obuf = (float*)d_ws;   // 512*512*32*4 = 33.5 MB

  rnn_k4<<<dim3(256), dim3(256), 0, stream>>>(
      x, emb, k0, r0, bi0, bh0, k1, r1, bi1, bh1,
      k2, r2, bi2, bh2, k3, r3, bi3, bh3,
      w1, b1, w2, b2, v, bv, wd, bd, out, obuf);
}

// Round 6
// 1332.806 us; speedup vs baseline: 3.4637x; 3.4637x over previous
//
#include <hip/hip_runtime.h>

#define TLEN 512
#define FIN 16

__device__ __forceinline__ float sigm(float x) { return 1.0f / (1.0f + __expf(-x)); }
__device__ __forceinline__ float tanh_f(float x) {
  x = fminf(fmaxf(x, -15.0f), 15.0f);
  float e = __expf(2.0f * x);
  return (e - 1.0f) / (e + 1.0f);
}

// Symmetric pair-finish for GRU: lanes (2g,2g+1) hold (z,r) gate sums; both
// compute the identical update via shfl_xor (no divergence, no barrier).
__device__ __forceinline__ float gru_fin(float own_main, float own_xh, float own_hhp,
                                         int role, float hold) {
  const float oth_main = __shfl_xor(own_main, 1);
  const float xh  = own_xh  + __shfl_xor(own_xh, 1);
  const float hhp = own_hhp + __shfl_xor(own_hhp, 1);
  const float sz = role ? oth_main : own_main;
  const float sr = role ? own_main : oth_main;
  const float z = sigm(sz);
  const float r = sigm(sr);
  const float hh = tanh_f(xh + r * hhp);
  return z * hold + (1.f - z) * hh;
}

// R6 = R2's verified 1-batch/block layer pipeline, but with launch_bounds(256,1)
// so the compiler allocates ~230 VGPR WITHOUT spilling (R2's (256,2) capped at
// 128 VGPR -> 350MB scratch traffic). Grid = 512 blocks -> 2 blocks/CU
// co-resident (VGPR<=256 -> 2 waves/SIMD, LDS ~20KB<=80KB) so each SIMD holds
// two same-role waves whose stalls interleave. R5 lesson: per-thread weight
// arrays must stay <=~192 floats (256 arch-VGPR ceiling).
//   w0: L0 units 0-31 (t=i)   + L3 A-partials (k3 . h2, t=i-3)
//   w1: L0 units 32-63 (t=i)  + input prefetch (t=i+2)
//   w2: L1 (t=i-1)
//   w3: L2 (t=i-2)            + L3 B-part + combine/update (t=i-4)
__global__ __launch_bounds__(256, 1)
void rnn_pipe(const float* __restrict__ x, const float* __restrict__ emb,
              const float* __restrict__ k0, const float* __restrict__ r0,
              const float* __restrict__ bi0, const float* __restrict__ bh0,
              const float* __restrict__ k1, const float* __restrict__ r1,
              const float* __restrict__ bi1, const float* __restrict__ bh1,
              const float* __restrict__ k2, const float* __restrict__ r2,
              const float* __restrict__ bi2, const float* __restrict__ bh2,
              const float* __restrict__ k3, const float* __restrict__ r3,
              const float* __restrict__ bi3, const float* __restrict__ bh3,
              const float* __restrict__ w1, const float* __restrict__ b1,
              const float* __restrict__ w2, const float* __restrict__ b2,
              const float* __restrict__ vv, const float* __restrict__ bv,
              const float* __restrict__ wd, const float* __restrict__ bd,
              float* __restrict__ out, float* __restrict__ obuf)
{
  __shared__ __align__(16) float s_h0[2][64];
  __shared__ __align__(16) float s_h1[2][32];
  __shared__ __align__(16) float s_h2[2][32];
  __shared__ __align__(16) float s_h3[2][32];
  __shared__ __align__(16) float s_inp[2][20];
  __shared__ __align__(16) float s_emb[TLEN][4];
  __shared__ __align__(16) float s_pA[2][64];
  __shared__ __align__(16) float s_pAh[2][64];
  // epilogue buffers
  __shared__ __align__(16) float e_w1[1024];
  __shared__ __align__(16) float e_sc[TLEN];
  __shared__ float e_hw2[32], e_b1[32], e_v[32], e_part[256], e_ctx[32];

  const int tid  = threadIdx.x;
  const int wid  = tid >> 6;
  const int lane = tid & 63;
  const int g    = lane >> 1;
  const int role = lane & 1;
  const int b    = blockIdx.x;

  float Wa[96], Wb[48], Wc[48];
  float bm = 0.f, bxh = 0.f, bhh = 0.f;
  float cbm = 0.f, cbxh = 0.f, cbhh = 0.f;
  float rxP = 0.f;

  // ---------------- weight loading (registers) ----------------
  if (wid <= 1) {                       // L0: unit u, gate-col cm
    const int u  = wid * 32 + g;
    const int cm = role ? 64 + u : u;
    #pragma unroll
    for (int j = 0; j < 19; ++j) Wa[j] = k0[j*192 + cm];
    Wa[19] = 0.f;
    #pragma unroll
    for (int j = 0; j < 64; ++j) Wa[20+j] = r0[j*192 + cm];
    #pragma unroll
    for (int jj = 0; jj < 10; ++jj) {
      const int row = role*10 + jj;
      Wb[jj] = (row < 19) ? k0[row*192 + 128 + u] : 0.f;
    }
    #pragma unroll
    for (int jj = 0; jj < 32; ++jj) Wb[10+jj] = r0[(role*32+jj)*192 + 128 + u];
    bm  = bi0[cm] + bh0[cm];
    bxh = role ? 0.f : bi0[128+u];
    bhh = role ? bh0[128+u] : 0.f;
  }
  if (wid == 0) {                       // L3 A-part: k3 over h2
    const int cma = role ? 32 + g : g;
    #pragma unroll
    for (int j = 0; j < 32; ++j) Wc[j] = k3[j*96 + cma];
    #pragma unroll
    for (int jj = 0; jj < 16; ++jj) Wc[32+jj] = k3[(role*16+jj)*96 + 64 + g];
  }
  if (wid == 2) {                       // L1
    const int cm = role ? 32 + g : g;
    #pragma unroll
    for (int j = 0; j < 64; ++j) Wa[j] = k1[j*96 + cm];
    #pragma unroll
    for (int j = 0; j < 32; ++j) Wa[64+j] = r1[j*96 + cm];
    #pragma unroll
    for (int jj = 0; jj < 32; ++jj) Wb[jj] = k1[(role*32+jj)*96 + 64 + g];
    #pragma unroll
    for (int jj = 0; jj < 16; ++jj) Wb[32+jj] = r1[(role*16+jj)*96 + 64 + g];
    bm  = bi1[cm] + bh1[cm];
    bxh = role ? 0.f : bi1[64+g];
    bhh = role ? bh1[64+g] : 0.f;
  }
  if (wid == 3) {                       // L2 + L3 B-part/combine
    const int cm = role ? 32 + g : g;
    #pragma unroll
    for (int j = 0; j < 32; ++j) Wa[j] = k2[j*96 + cm];
    #pragma unroll
    for (int j = 0; j < 32; ++j) Wa[32+j] = r2[j*96 + cm];
    #pragma unroll
    for (int jj = 0; jj < 16; ++jj) Wb[jj] = k2[(role*16+jj)*96 + 64 + g];
    #pragma unroll
    for (int jj = 0; jj < 16; ++jj) Wb[16+jj] = r2[(role*16+jj)*96 + 64 + g];
    bm  = bi2[cm] + bh2[cm];
    bxh = role ? 0.f : bi2[64+g];
    bhh = role ? bh2[64+g] : 0.f;
    #pragma unroll
    for (int j = 0; j < 32; ++j) Wc[j] = r3[j*96 + cm];
    #pragma unroll
    for (int jj = 0; jj < 16; ++jj) Wc[32+jj] = r3[(role*16+jj)*96 + 64 + g];
    cbm  = bi3[cm] + bh3[cm];
    cbxh = bi3[64+g];
    cbhh = bh3[64+g];
  }

  // ---------------- state init + embedding pre-gather ----------------
  if (tid < 64)       { s_h0[0][tid] = 0.f; s_h0[1][tid] = 0.f; }
  else if (tid < 96)  { const int q = tid-64;  s_h1[0][q]=0.f; s_h1[1][q]=0.f; }
  else if (tid < 128) { const int q = tid-96;  s_h2[0][q]=0.f; s_h2[1][q]=0.f; }
  else if (tid < 160) { const int q = tid-128; s_h3[0][q]=0.f; s_h3[1][q]=0.f; }
  else if (tid < 180) { const int q = tid-160; s_inp[0][q]=0.f; s_inp[1][q]=0.f; }

  for (int t2 = tid; t2 < TLEN; t2 += 256) {
    const int id = (int)x[((size_t)b*TLEN + t2)*FIN + 1];
    const float4 e4 = *(const float4*)&emb[id*4];
    *(float4*)&s_emb[t2][0] = e4;
  }
  if (wid == 1 && lane < 16) rxP = x[((size_t)b*TLEN + 1)*FIN + lane];
  __syncthreads();
  if (tid < 16) {                       // stage t=0 into slot 0
    const float v = x[((size_t)b*TLEN + 0)*FIN + tid];
    if (tid == 0) s_inp[0][0] = v;
    else if (tid >= 2) s_inp[0][tid-1] = v;
    if (tid < 4) s_inp[0][15+tid] = s_emb[0][tid];
  }

  // ---------------- pipelined recurrence ----------------
  for (int i = 0; i < 516; ++i) {
    __syncthreads();
    const int wp = i & 1;
    const int rp = wp ^ 1;

    if (wid <= 1) {
      if (i < 512) {                                    // ---- L0, t=i
        const int u = wid*32 + g;
        float a0 = bm, a1 = 0.f, a2 = 0.f, a3 = 0.f;
        #pragma unroll
        for (int j = 0; j < 20; j += 4) {
          const float4 q = *(const float4*)&s_inp[wp][j];
          a0 += Wa[j]*q.x; a1 += Wa[j+1]*q.y; a2 += Wa[j+2]*q.z; a3 += Wa[j+3]*q.w;
        }
        #pragma unroll
        for (int j = 0; j < 64; j += 4) {
          const float4 q = *(const float4*)&s_h0[rp][j];
          a0 += Wa[20+j]*q.x; a1 += Wa[21+j]*q.y; a2 += Wa[22+j]*q.z; a3 += Wa[23+j]*q.w;
        }
        float xq = bxh;
        #pragma unroll
        for (int jj = 0; jj < 10; ++jj) xq += Wb[jj]*s_inp[wp][role*10+jj];
        float p0 = bhh, p1 = 0.f;
        #pragma unroll
        for (int jj = 0; jj < 32; jj += 4) {
          const float4 q = *(const float4*)&s_h0[rp][role*32+jj];
          p0 += Wb[10+jj]*q.x + Wb[12+jj]*q.z;
          p1 += Wb[11+jj]*q.y + Wb[13+jj]*q.w;
        }
        const float hold = s_h0[rp][u];
        const float hn = gru_fin(a0+a1+a2+a3, xq, p0+p1, role, hold);
        if (!role) s_h0[wp][u] = hn;
      }
      if (wid == 0) {
        if (i >= 3 && i <= 514) {                       // ---- L3 A-part, t=i-3
          float q0=0.f,q1=0.f,q2=0.f,q3=0.f;
          #pragma unroll
          for (int j = 0; j < 32; j += 4) {
            const float4 q = *(const float4*)&s_h2[rp][j];
            q0 += Wc[j]*q.x; q1 += Wc[j+1]*q.y; q2 += Wc[j+2]*q.z; q3 += Wc[j+3]*q.w;
          }
          float ph0=0.f, ph1=0.f;
          #pragma unroll
          for (int jj = 0; jj < 16; jj += 4) {
            const float4 q = *(const float4*)&s_h2[rp][role*16+jj];
            ph0 += Wc[32+jj]*q.x + Wc[34+jj]*q.z;
            ph1 += Wc[33+jj]*q.y + Wc[35+jj]*q.w;
          }
          s_pA[wp][lane]  = q0+q1+q2+q3;
          s_pAh[wp][lane] = ph0+ph1;
        }
      } else {                                          // ---- w1: prefetch
        if (lane < 16) {
          if (i + 1 <= 511) {
            const int slot = (i+1)&1;
            const float v = rxP;
            if (lane == 0) s_inp[slot][0] = v;
            else if (lane >= 2) s_inp[slot][lane-1] = v;
            if (lane < 4) s_inp[slot][15+lane] = s_emb[i+1][lane];
          }
          if (i + 2 <= 511) rxP = x[((size_t)b*TLEN + (i+2))*FIN + lane];
        }
      }
    } else if (wid == 2) {
      if (i >= 1 && i <= 512) {                         // ---- L1, t=i-1
        float a0 = bm, a1=0.f, a2=0.f, a3=0.f;
        #pragma unroll
        for (int j = 0; j < 64; j += 4) {
          const float4 q = *(const float4*)&s_h0[rp][j];
          a0 += Wa[j]*q.x; a1 += Wa[j+1]*q.y; a2 += Wa[j+2]*q.z; a3 += Wa[j+3]*q.w;
        }
        #pragma unroll
        for (int j = 0; j < 32; j += 4) {
          const float4 q = *(const float4*)&s_h1[rp][j];
          a0 += Wa[64+j]*q.x; a1 += Wa[65+j]*q.y; a2 += Wa[66+j]*q.z; a3 += Wa[67+j]*q.w;
        }
        float x0 = bxh, x1 = 0.f;
        #pragma unroll
        for (int jj = 0; jj < 32; jj += 4) {
          const float4 q = *(const float4*)&s_h0[rp][role*32+jj];
          x0 += Wb[jj]*q.x + Wb[jj+2]*q.z;
          x1 += Wb[jj+1]*q.y + Wb[jj+3]*q.w;
        }
        float p0 = bhh, p1 = 0.f;
        #pragma unroll
        for (int jj = 0; jj < 16; jj += 4) {
          const float4 q = *(const float4*)&s_h1[rp][role*16+jj];
          p0 += Wb[32+jj]*q.x + Wb[34+jj]*q.z;
          p1 += Wb[33+jj]*q.y + Wb[35+jj]*q.w;
        }
        const float hold = s_h1[rp][g];
        const float hn = gru_fin(a0+a1+a2+a3, x0+x1, p0+p1, role, hold);
        if (!role) s_h1[wp][g] = hn;
      }
    } else {
      if (i >= 2 && i <= 513) {                         // ---- L2, t=i-2
        float a0 = bm, a1=0.f, a2=0.f, a3=0.f;
        #pragma unroll
        for (int j = 0; j < 32; j += 4) {
          const float4 q = *(const float4*)&s_h1[rp][j];
          a0 += Wa[j]*q.x; a1 += Wa[j+1]*q.y; a2 += Wa[j+2]*q.z; a3 += Wa[j+3]*q.w;
        }
        #pragma unroll
        for (int j = 0; j < 32; j += 4) {
          const float4 q = *(const float4*)&s_h2[rp][j];
          a0 += Wa[32+j]*q.x; a1 += Wa[33+j]*q.y; a2 += Wa[34+j]*q.z; a3 += Wa[35+j]*q.w;
        }
        float x0 = bxh, x1 = 0.f;
        #pragma unroll
        for (int jj = 0; jj < 16; jj += 4) {
          const float4 q = *(const float4*)&s_h1[rp][role*16+jj];
          x0 += Wb[jj]*q.x + Wb[jj+2]*q.z;
          x1 += Wb[jj+1]*q.y + Wb[jj+3]*q.w;
        }
        float p0 = bhh, p1 = 0.f;
        #pragma unroll
        for (int jj = 0; jj < 16; jj += 4) {
          const float4 q = *(const float4*)&s_h2[rp][role*16+jj];
          p0 += Wb[16+jj]*q.x + Wb[18+jj]*q.z;
          p1 += Wb[17+jj]*q.y + Wb[19+jj]*q.w;
        }
        const float hold = s_h2[rp][g];
        const float hn = gru_fin(a0+a1+a2+a3, x0+x1, p0+p1, role, hold);
        if (!role) s_h2[wp][g] = hn;
      }
      if (i >= 4) {                                     // ---- L3 B + combine, t=i-4
        float q0=0.f,q1=0.f,q2=0.f,q3=0.f;
        #pragma unroll
        for (int j = 0; j < 32; j += 4) {
          const float4 q = *(const float4*)&s_h3[rp][j];
          q0 += Wc[j]*q.x; q1 += Wc[j+1]*q.y; q2 += Wc[j+2]*q.z; q3 += Wc[j+3]*q.w;
        }
        float ph0=0.f, ph1=0.f;
        #pragma unroll
        for (int jj = 0; jj < 16; jj += 4) {
          const float4 q = *(const float4*)&s_h3[rp][role*16+jj];
          ph0 += Wc[32+jj]*q.x + Wc[34+jj]*q.z;
          ph1 += Wc[33+jj]*q.y + Wc[35+jj]*q.w;
        }
        const float own_main = s_pA[rp][lane] + (q0+q1+q2+q3) + cbm;
        const float ownxh = s_pAh[rp][lane];
        const float ownph = ph0 + ph1;
        const float oth_main = __shfl_xor(own_main, 1);
        const float xh  = ownxh + __shfl_xor(ownxh, 1) + cbxh;
        const float hhp = ownph + __shfl_xor(ownph, 1) + cbhh;
        const float sz = role ? oth_main : own_main;
        const float sr = role ? own_main : oth_main;
        const float z = sigm(sz);
        const float r = sigm(sr);
        const float hh = tanh_f(xh + r*hhp);
        const float hold = s_h3[rp][g];
        const float hn = z*hold + (1.f-z)*hh;
        if (!role) {
          s_h3[wp][g] = hn;
          obuf[((size_t)b*TLEN + (i-4))*32 + g] = hn;
        }
      }
    }
  }
  __syncthreads();

  // ---------------- attention epilogue (hT = s_h3[1]) ----------------
  for (int kk = tid; kk < 1024; kk += 256) e_w1[kk] = w1[kk];
  if (tid < 32) { e_b1[tid] = b1[tid]; e_v[tid] = vv[tid]; }
  if (tid >= 64 && tid < 96) {
    const int u = tid - 64;
    float s = b2[u];
    #pragma unroll
    for (int j = 0; j < 32; ++j) s += s_h3[1][j] * w2[j*32 + u];
    e_hw2[u] = s;
  }
  __syncthreads();

  #pragma unroll
  for (int c = 0; c < 2; ++c) {
    const int t2 = c*256 + tid;
    const float* row = obuf + ((size_t)b*TLEN + t2)*32;
    float rr[32];
    #pragma unroll
    for (int j = 0; j < 32; j += 4) {
      const float4 r4 = *(const float4*)&row[j];
      rr[j]=r4.x; rr[j+1]=r4.y; rr[j+2]=r4.z; rr[j+3]=r4.w;
    }
    float sc = 0.f;
    for (int u = 0; u < 32; ++u) {
      float qv = e_b1[u] + e_hw2[u];
      #pragma unroll
      for (int j = 0; j < 32; ++j) qv += rr[j]*e_w1[j*32+u];
      sc += tanh_f(qv)*e_v[u];
    }
    e_sc[t2] = sc;    // bv dropped: constant shift cancels in softmax
  }
  __syncthreads();

  if (tid < 64) {     // softmax over T (wave 0)
    float sv[8]; float m = -1e30f;
    #pragma unroll
    for (int k = 0; k < 8; ++k) { sv[k] = e_sc[tid + 64*k]; m = fmaxf(m, sv[k]); }
    #pragma unroll
    for (int off = 32; off > 0; off >>= 1) m = fmaxf(m, __shfl_xor(m, off));
    float ss = 0.f;
    #pragma unroll
    for (int k = 0; k < 8; ++k) { sv[k] = __expf(sv[k]-m); ss += sv[k]; }
    #pragma unroll
    for (int off = 32; off > 0; off >>= 1) ss += __shfl_xor(ss, off);
    const float inv = 1.f/ss;
    #pragma unroll
    for (int k = 0; k < 8; ++k) e_sc[tid + 64*k] = sv[k]*inv;
  }
  __syncthreads();

  {                   // ctx partial sums (coalesced over u)
    const int u = tid & 31, ch = tid >> 5;
    float acc = 0.f;
    const float* orow = obuf + ((size_t)b*TLEN + ch*64)*32 + u;
    #pragma unroll 4
    for (int t2 = 0; t2 < 64; ++t2) acc += e_sc[ch*64+t2]*orow[(size_t)t2*32];
    e_part[ch*32+u] = acc;
  }
  __syncthreads();
  if (tid < 32) {
    float acc = 0.f;
    #pragma unroll
    for (int ch = 0; ch < 8; ++ch) acc += e_part[ch*32+tid];
    e_ctx[tid] = acc;
  }
  __syncthreads();
  if (tid == 0) {
    float l0 = bd[0], l1 = bd[1];
    #pragma unroll
    for (int u = 0; u < 32; ++u) { l0 += e_ctx[u]*wd[u*2]; l1 += e_ctx[u]*wd[u*2+1]; }
    const float mm = fmaxf(l0,l1);
    const float ex0 = __expf(l0-mm), ex1 = __expf(l1-mm);
    out[b*2+0] = ex0/(ex0+ex1);
    out[b*2+1] = ex1/(ex0+ex1);
  }
}

extern "C" void kernel_launch(void* const* d_in, const int* in_sizes, int n_in,
                              void* d_out, int out_size, void* d_ws, size_t ws_size,
                              hipStream_t stream) {
  const float* x   = (const float*)d_in[0];
  const float* emb = (const float*)d_in[1];
  const float* k0  = (const float*)d_in[2];
  const float* r0  = (const float*)d_in[3];
  const float* bi0 = (const float*)d_in[4];
  const float* bh0 = (const float*)d_in[5];
  const float* k1  = (const float*)d_in[6];
  const float* r1  = (const float*)d_in[7];
  const float* bi1 = (const float*)d_in[8];
  const float* bh1 = (const float*)d_in[9];
  const float* k2  = (const float*)d_in[10];
  const float* r2  = (const float*)d_in[11];
  const float* bi2 = (const float*)d_in[12];
  const float* bh2 = (const float*)d_in[13];
  const float* k3  = (const float*)d_in[14];
  const float* r3  = (const float*)d_in[15];
  const float* bi3 = (const float*)d_in[16];
  const float* bh3 = (const float*)d_in[17];
  const float* w1  = (const float*)d_in[18];
  const float* b1  = (const float*)d_in[19];
  const float* w2  = (const float*)d_in[20];
  const float* b2  = (const float*)d_in[21];
  const float* v   = (const float*)d_in[22];
  const float* bv  = (const float*)d_in[23];
  const float* wd  = (const float*)d_in[24];
  const float* bd  = (const float*)d_in[25];

  float* out  = (float*)d_out;
  float* obuf = (float*)d_ws;   // 512*512*32*4 = 33.5 MB

  rnn_pipe<<<dim3(512), dim3(256), 0, stream>>>(
      x, emb, k0, r0, bi0, bh0, k1, r1, bi1, bh1,
      k2, r2, bi2, bh2, k3, r3, bi3, bh3,
      w1, b1, w2, b2, v, bv, wd, bd, out, obuf);
}